// Round 16
// baseline (290.607 us; speedup 1.0000x reference)
//
#include <hip/hip_runtime.h>

#define B_  4
#define C_  256     // C_IN == LATENT == 256
#define N_  4096    // H*W
#define SCALE 0.0625f   // 1/sqrt(256)

typedef short s8v __attribute__((ext_vector_type(8)));
typedef float f4v __attribute__((ext_vector_type(4)));

// round-to-nearest-even fp32 -> bf16 (values are finite; no NaN handling needed)
static __device__ __forceinline__ ushort f2bf(float f) {
  union { float f; uint u; } v; v.f = f;
  return (ushort)((v.u + 0x7FFFu + ((v.u >> 16) & 1u)) >> 16);
}

// ---------------------------------------------------------------------------
// xpose_cast: x [b][c][n] fp32 -> x_t [b][n][c] bf16 + fused den zeroing.
// (R13-exact). grid (64, 4, 4).
// ---------------------------------------------------------------------------
__global__ __launch_bounds__(256) void xpose_cast(
    const float* __restrict__ x, ushort* __restrict__ x_t,
    float* __restrict__ den)
{
  const int b  = blockIdx.z;
  const int c0 = blockIdx.y * 64;
  const int n0 = blockIdx.x * 64;
  __shared__ float t[64][65];

  if (blockIdx.y == 0 && threadIdx.x < 64)
    den[b * N_ + n0 + threadIdx.x] = 0.f;

  const int tc = threadIdx.x >> 4;
  const int tn = (threadIdx.x & 15) * 4;
  #pragma unroll
  for (int cc = 0; cc < 64; cc += 16) {
    float4 v = *(const float4*)(x + (size_t)(b * C_ + c0 + cc + tc) * N_ + n0 + tn);
    t[cc + tc][tn + 0] = v.x;
    t[cc + tc][tn + 1] = v.y;
    t[cc + tc][tn + 2] = v.z;
    t[cc + tc][tn + 3] = v.w;
  }
  __syncthreads();

  const int on = threadIdx.x >> 2;
  const int oc = (threadIdx.x & 3) * 16;
  union { ushort us[16]; uint4 q[2]; } o;
  #pragma unroll
  for (int i = 0; i < 16; ++i) o.us[i] = f2bf(t[oc + i][on]);
  ushort* dst = x_t + (size_t)(b * N_ + n0 + on) * C_ + c0 + oc;
  *(uint4*)dst       = o.q[0];
  *(uint4*)(dst + 8) = o.q[1];
}

// ---------------------------------------------------------------------------
// qkv_mfma: bf16 MFMA projection (R13-exact). grid (8, 4, 12), block 256.
// ---------------------------------------------------------------------------
__global__ __launch_bounds__(256, 2) void qkv_mfma(
    const ushort* __restrict__ x_t,
    const float* __restrict__ Wq, const float* __restrict__ bq,
    const float* __restrict__ Wk, const float* __restrict__ bk,
    const float* __restrict__ Wv, const float* __restrict__ bv,
    ushort* __restrict__ q_t, ushort* __restrict__ k_t, ushort* __restrict__ v_bf)
{
  const int p = blockIdx.z >> 2;
  const int b = blockIdx.z & 3;
  const float* W  = (p == 0) ? Wq : (p == 1) ? Wk : Wv;
  const float* bi = (p == 0) ? bq : (p == 1) ? bk : bv;
  const int l0    = blockIdx.y * 64;
  const int nseg  = blockIdx.x * 512;

  const int tid  = threadIdx.x;
  const int lane = tid & 63;
  const int wave = tid >> 6;
  const int l16  = lane & 15;
  const int quad = lane >> 4;

  __shared__ __align__(16) ushort w_lds[64 * 264];
  __shared__ __align__(16) ushort x_lds[64 * 264];

  for (int g = tid; g < 4096; g += 256) {
    int row = g >> 6, col4 = (g & 63) * 4;
    float4 wv = *(const float4*)(W + (size_t)(l0 + row) * 256 + col4);
    *(ushort4*)&w_lds[row * 264 + col4] =
        make_ushort4(f2bf(wv.x), f2bf(wv.y), f2bf(wv.z), f2bf(wv.w));
  }
  __syncthreads();

  s8v kw[4][8];
  #pragma unroll
  for (int lt = 0; lt < 4; ++lt)
    #pragma unroll
    for (int cs = 0; cs < 8; ++cs)
      kw[lt][cs] = *(const s8v*)&w_lds[(lt * 16 + l16) * 264 + quad * 8 + cs * 32];

  float bias_l[4];
  #pragma unroll
  for (int lt = 0; lt < 4; ++lt) bias_l[lt] = bi[l0 + lt * 16 + l16];

  for (int it = 0; it < 8; ++it) {
    const int n0 = nseg + it * 64;
    {
      const ushort* xseg = x_t + (size_t)(b * N_ + n0) * C_;
      #pragma unroll
      for (int k = 0; k < 8; ++k) {
        int c = tid + k * 256;
        uint4 d = *(const uint4*)(xseg + (size_t)c * 8);
        *(uint4*)&x_lds[(c >> 5) * 264 + (c & 31) * 8] = d;
      }
    }
    __syncthreads();

    f4v s[4];
    #pragma unroll
    for (int lt = 0; lt < 4; ++lt) s[lt] = (f4v){0.f, 0.f, 0.f, 0.f};
    const ushort* xa_base = x_lds + (wave * 16 + l16) * 264 + quad * 8;
    #pragma unroll
    for (int cs = 0; cs < 8; ++cs) {
      s8v xa = *(const s8v*)(xa_base + cs * 32);
      #pragma unroll
      for (int lt = 0; lt < 4; ++lt)
        s[lt] = __builtin_amdgcn_mfma_f32_16x16x32_bf16(xa, kw[lt][cs], s[lt], 0, 0, 0);
    }

    const int nb = n0 + wave * 16 + quad * 4;
    if (p < 2) {
      ushort* outp = (p == 0) ? q_t : k_t;
      #pragma unroll
      for (int lt = 0; lt < 4; ++lt) {
        const int l = l0 + lt * 16 + l16;
        #pragma unroll
        for (int r = 0; r < 4; ++r)
          outp[(size_t)(b * N_ + nb + r) * C_ + l] = f2bf(s[lt][r] + bias_l[lt]);
      }
    } else {
      #pragma unroll
      for (int lt = 0; lt < 4; ++lt) {
        const int c_out = l0 + lt * 16 + l16;
        *(ushort4*)&v_bf[(size_t)(b * C_ + c_out) * N_ + nb] =
            make_ushort4(f2bf(s[lt][0] + bias_l[lt]), f2bf(s[lt][1] + bias_l[lt]),
                         f2bf(s[lt][2] + bias_l[lt]), f2bf(s[lt][3] + bias_l[lt]));
      }
    }
    __syncthreads();
  }
}

// ---------------------------------------------------------------------------
// flash8d: flash8b with PV c-widening to halve P LDS reads.
//   QK side R13-exact. PV reassignment: wave owns 8 c-tiles x 2 tj-tiles
//   (was 4 x 4): pb per ks drops 4 -> 2 b128 (P-read 32 -> 16 KB/block-iter;
//   total LDS 136 -> 120 KB). av widens to [8][2] (64 VGPR); unified budget
//   ~ 64 kf + 64 av + 8 pb + ~20 temps + 64 acc = ~220 <= 256 (no spill).
//   Coverage: w0(c0-127,tj0-31) w1(c128-255,tj0-31) w2(c0-127,tj32-63)
//   w3(c128-255,tj32-63) — disjoint union of [64 tj][256 c].
// grid (64, 2, 4) = (tj-blocks, i-segments, batch), block 256 (4 waves).
// ---------------------------------------------------------------------------
__global__ __launch_bounds__(256, 2) void flash8d(
    const ushort* __restrict__ q_t, const ushort* __restrict__ k_t,
    const ushort* __restrict__ v_bf, ushort* __restrict__ res0,
    ushort* __restrict__ res1, float* __restrict__ den)
{
  const int tid  = threadIdx.x;
  const int lane = tid & 63;
  const int wave = tid >> 6;
  const int l16  = lane & 15;
  const int quad = lane >> 4;
  const int jw    = blockIdx.x * 64;         // block tj base
  const int seg   = blockIdx.y;
  const int ibase = seg * 2048;              // i-segment base
  const int b     = blockIdx.z;

  const int wqk_j = wave & 1;                // QK: tj-pair (tj = wqk_j*32 + jt*16)
  const int wqk_i = wave >> 1;               // QK: i-pair  (i_loc = (wqk_i*2+itile)*16)
  const int wpv_c = wave & 1;                // PV: c-range wpv_c*128 (8 c-tiles)
  const int wpv_j = wave >> 1;               // PV: tj-range wpv_j*32 (2 tj-tiles)

  __shared__ __align__(16) ushort q_lds[64 * 264];   // [i][c], +8 pad/row; reused by epilogue
  __shared__ __align__(16) ushort p_lds[64 * 72];    // [tj][ti], +8 pad/row

  // K fragments: wave's 32 tj x 256 c, resident whole kernel (64 VGPR)
  s8v kf[2][8];
  #pragma unroll
  for (int jt = 0; jt < 2; ++jt) {
    const ushort* kp = k_t + (size_t)(b * N_ + jw + wqk_j * 32 + jt * 16 + l16) * C_ + quad * 8;
    #pragma unroll
    for (int cs = 0; cs < 8; ++cs) kf[jt][cs] = *(const s8v*)(kp + cs * 32);
  }

  f4v acc[8][2];   // [m: c-tile][t: tj-tile]; c = wpv_c*128+m*16+quad*4+r, tj = jw+wpv_j*32+t*16+l16
  #pragma unroll
  for (int m = 0; m < 8; ++m)
    #pragma unroll
    for (int t = 0; t < 2; ++t) acc[m][t] = (f4v){0.f, 0.f, 0.f, 0.f};
  float dacc0 = 0.f, dacc1 = 0.f;

  const ushort* vbase0 = v_bf + (size_t)(b * C_ + wpv_c * 128 + l16) * N_ + quad * 8;

  for (int it = 0; it < 32; ++it) {
    const int i0 = ibase + it * 64;

    // stage q-chunk [64 i][256 c] -> LDS (8 x 16B chunks per thread)
    {
      const ushort* qseg = q_t + ((size_t)(b * N_) + i0) * C_;
      #pragma unroll
      for (int k = 0; k < 8; ++k) {
        int c = tid + k * 256;
        uint4 d = *(const uint4*)(qseg + (size_t)c * 8);
        *(uint4*)&q_lds[(c >> 5) * 264 + (c & 31) * 8] = d;
      }
    }

    // v A-frags (8 c-tiles x 2 ks): issue now, consumed after P-barrier
    s8v av[8][2];
    #pragma unroll
    for (int m = 0; m < 8; ++m)
      #pragma unroll
      for (int ks = 0; ks < 2; ++ks)
        av[m][ks] = *(const s8v*)(vbase0 + (size_t)(m * 16) * N_ + i0 + ks * 32);

    __syncthreads();   // q ready

    // QK: 2 i-tiles x 2 tj-tiles, A from LDS, B from registers (R13-exact)
    #pragma unroll
    for (int itile = 0; itile < 2; ++itile) {
      const int i_loc = (wqk_i * 2 + itile) * 16;
      f4v s0 = (f4v){0.f, 0.f, 0.f, 0.f};
      f4v s1 = (f4v){0.f, 0.f, 0.f, 0.f};
      const ushort* qa_base = q_lds + (i_loc + l16) * 264 + quad * 8;
      #pragma unroll
      for (int cs = 0; cs < 8; ++cs) {
        s8v qa = *(const s8v*)(qa_base + cs * 32);
        s0 = __builtin_amdgcn_mfma_f32_16x16x32_bf16(qa, kf[0][cs], s0, 0, 0, 0);
        s1 = __builtin_amdgcn_mfma_f32_16x16x32_bf16(qa, kf[1][cs], s1, 0, 0, 0);
      }
      {
        float e0 = __expf(s0[0] * SCALE), e1 = __expf(s0[1] * SCALE);
        float e2 = __expf(s0[2] * SCALE), e3 = __expf(s0[3] * SCALE);
        dacc0 += (e0 + e1) + (e2 + e3);
        *(ushort4*)&p_lds[(wqk_j * 32 + l16) * 72 + i_loc + quad * 4] =
            make_ushort4(f2bf(e0), f2bf(e1), f2bf(e2), f2bf(e3));
      }
      {
        float e0 = __expf(s1[0] * SCALE), e1 = __expf(s1[1] * SCALE);
        float e2 = __expf(s1[2] * SCALE), e3 = __expf(s1[3] * SCALE);
        dacc1 += (e0 + e1) + (e2 + e3);
        *(ushort4*)&p_lds[(wqk_j * 32 + 16 + l16) * 72 + i_loc + quad * 4] =
            make_ushort4(f2bf(e0), f2bf(e1), f2bf(e2), f2bf(e3));
      }
    }

    __syncthreads();   // P ready (also drains av loads)

    // PV: 8 c-tiles x 2 tj-tiles, A = av regs, B from p_lds (2 b128 per ks)
    #pragma unroll
    for (int ks = 0; ks < 2; ++ks) {
      s8v pb[2];
      #pragma unroll
      for (int t = 0; t < 2; ++t)
        pb[t] = *(const s8v*)&p_lds[(wpv_j * 32 + t * 16 + l16) * 72 + ks * 32 + quad * 8];
      #pragma unroll
      for (int m = 0; m < 8; ++m)
        #pragma unroll
        for (int t = 0; t < 2; ++t)
          acc[m][t] = __builtin_amdgcn_mfma_f32_16x16x32_bf16(av[m][ks], pb[t], acc[m][t], 0, 0, 0);
    }
  }

  // ---- denom: lanes l, l^16, l^32 share tj; butterfly then atomic ----
  dacc0 += __shfl_xor(dacc0, 16);  dacc0 += __shfl_xor(dacc0, 32);
  dacc1 += __shfl_xor(dacc1, 16);  dacc1 += __shfl_xor(dacc1, 32);
  if (lane < 16) {
    atomicAdd(&den[b * N_ + jw + wqk_j * 32 + lane], dacc0);
    atomicAdd(&den[b * N_ + jw + wqk_j * 32 + 16 + lane], dacc1);
  }

  // ---- epilogue: assemble [64 j][256 c] tile in q_lds, coalesced store ----
  #pragma unroll
  for (int m = 0; m < 8; ++m) {
    const int c0 = wpv_c * 128 + m * 16 + quad * 4;
    #pragma unroll
    for (int t = 0; t < 2; ++t) {
      *(ushort4*)&q_lds[(wpv_j * 32 + t * 16 + l16) * 264 + c0] =
          make_ushort4(f2bf(acc[m][t][0]), f2bf(acc[m][t][1]),
                       f2bf(acc[m][t][2]), f2bf(acc[m][t][3]));
    }
  }
  __syncthreads();   // tile assembled
  {
    ushort* rp = (seg ? res1 : res0) + (size_t)(b * N_ + jw) * C_;
    #pragma unroll
    for (int k = 0; k < 8; ++k) {
      int c = tid + k * 256;                 // 2048 16B-chunks
      int row = c >> 5, col = (c & 31) * 8;
      uint4 d = *(const uint4*)&q_lds[row * 264 + col];
      *(uint4*)&rp[(size_t)row * C_ + col] = d;
    }
  }
}

// ---------------------------------------------------------------------------
// out_mfma: out[b][co][n] = bo[co] + Wo[co][:]·(res0+res1)[b][n][:] / den[b][n]
// (R13-exact). grid (16, 4, 4), block 256.
// ---------------------------------------------------------------------------
__global__ __launch_bounds__(256, 2) void out_mfma(
    const ushort* __restrict__ res0, const ushort* __restrict__ res1,
    const float* __restrict__ Wo, const float* __restrict__ bo,
    const float* __restrict__ den, float* __restrict__ out)
{
  const int b    = blockIdx.z;
  const int co0  = blockIdx.y * 64;
  const int nseg = blockIdx.x * 256;

  const int tid  = threadIdx.x;
  const int lane = tid & 63;
  const int wave = tid >> 6;
  const int l16  = lane & 15;
  const int quad = lane >> 4;

  __shared__ __align__(16) ushort w_lds[64 * 264];
  __shared__ __align__(16) ushort r_lds[2][64 * 264];

  for (int g = tid; g < 4096; g += 256) {
    int row = g >> 6, col4 = (g & 63) * 4;
    float4 wv = *(const float4*)(Wo + (size_t)(co0 + row) * 256 + col4);
    *(ushort4*)&w_lds[row * 264 + col4] =
        make_ushort4(f2bf(wv.x), f2bf(wv.y), f2bf(wv.z), f2bf(wv.w));
  }
  __syncthreads();

  s8v kw[4][8];
  #pragma unroll
  for (int lt = 0; lt < 4; ++lt)
    #pragma unroll
    for (int cs = 0; cs < 8; ++cs)
      kw[lt][cs] = *(const s8v*)&w_lds[(lt * 16 + l16) * 264 + quad * 8 + cs * 32];

  float bias_l[4];
  #pragma unroll
  for (int lt = 0; lt < 4; ++lt) bias_l[lt] = bo[co0 + lt * 16 + l16];

  for (int it = 0; it < 4; ++it) {
    const int n0 = nseg + it * 64;
    {
      const ushort* r0 = res0 + (size_t)(b * N_ + n0) * C_;
      const ushort* r1 = res1 + (size_t)(b * N_ + n0) * C_;
      #pragma unroll
      for (int k = 0; k < 8; ++k) {
        int c = tid + k * 256;
        uint4 d0 = *(const uint4*)(r0 + (size_t)c * 8);
        uint4 d1 = *(const uint4*)(r1 + (size_t)c * 8);
        *(uint4*)&r_lds[0][(c >> 5) * 264 + (c & 31) * 8] = d0;
        *(uint4*)&r_lds[1][(c >> 5) * 264 + (c & 31) * 8] = d1;
      }
    }
    __syncthreads();

    f4v s[4];
    #pragma unroll
    for (int lt = 0; lt < 4; ++lt) s[lt] = (f4v){0.f, 0.f, 0.f, 0.f};
    #pragma unroll
    for (int buf = 0; buf < 2; ++buf) {
      const ushort* ra_base = r_lds[buf] + (wave * 16 + l16) * 264 + quad * 8;
      #pragma unroll
      for (int cs = 0; cs < 8; ++cs) {
        s8v ra = *(const s8v*)(ra_base + cs * 32);
        #pragma unroll
        for (int lt = 0; lt < 4; ++lt)
          s[lt] = __builtin_amdgcn_mfma_f32_16x16x32_bf16(ra, kw[lt][cs], s[lt], 0, 0, 0);
      }
    }

    const int nb = n0 + wave * 16 + quad * 4;
    float4 dv = *(const float4*)(den + (size_t)b * N_ + nb);
    const float di0 = 1.0f / dv.x, di1 = 1.0f / dv.y, di2 = 1.0f / dv.z, di3 = 1.0f / dv.w;
    #pragma unroll
    for (int lt = 0; lt < 4; ++lt) {
      const int co = co0 + lt * 16 + l16;
      *(float4*)&out[(size_t)(b * C_ + co) * N_ + nb] =
          make_float4(s[lt][0] * di0 + bias_l[lt], s[lt][1] * di1 + bias_l[lt],
                      s[lt][2] * di2 + bias_l[lt], s[lt][3] * di3 + bias_l[lt]);
    }
    __syncthreads();
  }
}

// ---------------------------------------------------------------------------
extern "C" void kernel_launch(void* const* d_in, const int* in_sizes, int n_in,
                              void* d_out, int out_size, void* d_ws, size_t ws_size,
                              hipStream_t stream)
{
  const float* x  = (const float*)d_in[0];
  const float* Wq = (const float*)d_in[1];
  const float* bq = (const float*)d_in[2];
  const float* Wk = (const float*)d_in[3];
  const float* bk = (const float*)d_in[4];
  const float* Wv = (const float*)d_in[5];
  const float* bv = (const float*)d_in[6];
  const float* Wo = (const float*)d_in[7];
  const float* bo = (const float*)d_in[8];
  float* out = (float*)d_out;

  // workspace layout (~48.1 MB):
  //   q_t   [B][N][L] bf16 : 8 MB   (transposed)
  //   k_t   [B][N][L] bf16 : 8 MB   (transposed)
  //   v_bf  [B][L][N] bf16 : 8 MB   (natural)
  //   res0  [B][N][L] bf16 : 8 MB   (numerator partial, i-segment 0)
  //   res1  [B][N][L] bf16 : 8 MB   (numerator partial, i-segment 1)
  //   den   [B][N]    fp32 : 64 KB  (softmax denominators; zeroed in xpose_cast)
  //   x_t   [B][N][C] bf16 : 8 MB   (transposed+cast input)
  char* ws = (char*)d_ws;
  ushort* q_t  = (ushort*)(ws);
  ushort* k_t  = (ushort*)(ws + (size_t)8  * 1024 * 1024);
  ushort* v_bf = (ushort*)(ws + (size_t)16 * 1024 * 1024);
  ushort* res0 = (ushort*)(ws + (size_t)24 * 1024 * 1024);
  ushort* res1 = (ushort*)(ws + (size_t)32 * 1024 * 1024);
  float*  den  = (float*) (ws + (size_t)40 * 1024 * 1024);
  ushort* x_t  = (ushort*)(ws + (size_t)40 * 1024 * 1024 + 65536);

  xpose_cast<<<dim3(64, 4, 4), dim3(256), 0, stream>>>(x, x_t, den);
  qkv_mfma <<<dim3(8, 4, 12),  dim3(256), 0, stream>>>(x_t, Wq, bq, Wk, bk, Wv, bv, q_t, k_t, v_bf);
  flash8d  <<<dim3(64, 2, 4),  dim3(256), 0, stream>>>(q_t, k_t, v_bf, res0, res1, den);
  out_mfma <<<dim3(16, 4, 4),  dim3(256), 0, stream>>>(res0, res1, Wo, bo, den, out);
}

// Round 17
// 203.992 us; speedup vs baseline: 1.4246x; 1.4246x over previous
//
#include <hip/hip_runtime.h>

#define B_  4
#define C_  256     // C_IN == LATENT == 256
#define N_  4096    // H*W
#define SCALE 0.0625f   // 1/sqrt(256)

typedef short s8v __attribute__((ext_vector_type(8)));
typedef float f4v __attribute__((ext_vector_type(4)));

// round-to-nearest-even fp32 -> bf16 (values are finite; no NaN handling needed)
static __device__ __forceinline__ ushort f2bf(float f) {
  union { float f; uint u; } v; v.f = f;
  return (ushort)((v.u + 0x7FFFu + ((v.u >> 16) & 1u)) >> 16);
}

// ---------------------------------------------------------------------------
// xpose_cast: x [b][c][n] fp32 -> x_t [b][n][c] bf16 + fused den zeroing.
// (R13-exact). grid (64, 4, 4).
// ---------------------------------------------------------------------------
__global__ __launch_bounds__(256) void xpose_cast(
    const float* __restrict__ x, ushort* __restrict__ x_t,
    float* __restrict__ den)
{
  const int b  = blockIdx.z;
  const int c0 = blockIdx.y * 64;
  const int n0 = blockIdx.x * 64;
  __shared__ float t[64][65];

  if (blockIdx.y == 0 && threadIdx.x < 64)
    den[b * N_ + n0 + threadIdx.x] = 0.f;

  const int tc = threadIdx.x >> 4;
  const int tn = (threadIdx.x & 15) * 4;
  #pragma unroll
  for (int cc = 0; cc < 64; cc += 16) {
    float4 v = *(const float4*)(x + (size_t)(b * C_ + c0 + cc + tc) * N_ + n0 + tn);
    t[cc + tc][tn + 0] = v.x;
    t[cc + tc][tn + 1] = v.y;
    t[cc + tc][tn + 2] = v.z;
    t[cc + tc][tn + 3] = v.w;
  }
  __syncthreads();

  const int on = threadIdx.x >> 2;
  const int oc = (threadIdx.x & 3) * 16;
  union { ushort us[16]; uint4 q[2]; } o;
  #pragma unroll
  for (int i = 0; i < 16; ++i) o.us[i] = f2bf(t[oc + i][on]);
  ushort* dst = x_t + (size_t)(b * N_ + n0 + on) * C_ + c0 + oc;
  *(uint4*)dst       = o.q[0];
  *(uint4*)(dst + 8) = o.q[1];
}

// ---------------------------------------------------------------------------
// qkv_mfma: bf16 MFMA projection (R13-exact). grid (8, 4, 12), block 256.
// ---------------------------------------------------------------------------
__global__ __launch_bounds__(256, 2) void qkv_mfma(
    const ushort* __restrict__ x_t,
    const float* __restrict__ Wq, const float* __restrict__ bq,
    const float* __restrict__ Wk, const float* __restrict__ bk,
    const float* __restrict__ Wv, const float* __restrict__ bv,
    ushort* __restrict__ q_t, ushort* __restrict__ k_t, ushort* __restrict__ v_bf)
{
  const int p = blockIdx.z >> 2;
  const int b = blockIdx.z & 3;
  const float* W  = (p == 0) ? Wq : (p == 1) ? Wk : Wv;
  const float* bi = (p == 0) ? bq : (p == 1) ? bk : bv;
  const int l0    = blockIdx.y * 64;
  const int nseg  = blockIdx.x * 512;

  const int tid  = threadIdx.x;
  const int lane = tid & 63;
  const int wave = tid >> 6;
  const int l16  = lane & 15;
  const int quad = lane >> 4;

  __shared__ __align__(16) ushort w_lds[64 * 264];
  __shared__ __align__(16) ushort x_lds[64 * 264];

  for (int g = tid; g < 4096; g += 256) {
    int row = g >> 6, col4 = (g & 63) * 4;
    float4 wv = *(const float4*)(W + (size_t)(l0 + row) * 256 + col4);
    *(ushort4*)&w_lds[row * 264 + col4] =
        make_ushort4(f2bf(wv.x), f2bf(wv.y), f2bf(wv.z), f2bf(wv.w));
  }
  __syncthreads();

  s8v kw[4][8];
  #pragma unroll
  for (int lt = 0; lt < 4; ++lt)
    #pragma unroll
    for (int cs = 0; cs < 8; ++cs)
      kw[lt][cs] = *(const s8v*)&w_lds[(lt * 16 + l16) * 264 + quad * 8 + cs * 32];

  float bias_l[4];
  #pragma unroll
  for (int lt = 0; lt < 4; ++lt) bias_l[lt] = bi[l0 + lt * 16 + l16];

  for (int it = 0; it < 8; ++it) {
    const int n0 = nseg + it * 64;
    {
      const ushort* xseg = x_t + (size_t)(b * N_ + n0) * C_;
      #pragma unroll
      for (int k = 0; k < 8; ++k) {
        int c = tid + k * 256;
        uint4 d = *(const uint4*)(xseg + (size_t)c * 8);
        *(uint4*)&x_lds[(c >> 5) * 264 + (c & 31) * 8] = d;
      }
    }
    __syncthreads();

    f4v s[4];
    #pragma unroll
    for (int lt = 0; lt < 4; ++lt) s[lt] = (f4v){0.f, 0.f, 0.f, 0.f};
    const ushort* xa_base = x_lds + (wave * 16 + l16) * 264 + quad * 8;
    #pragma unroll
    for (int cs = 0; cs < 8; ++cs) {
      s8v xa = *(const s8v*)(xa_base + cs * 32);
      #pragma unroll
      for (int lt = 0; lt < 4; ++lt)
        s[lt] = __builtin_amdgcn_mfma_f32_16x16x32_bf16(xa, kw[lt][cs], s[lt], 0, 0, 0);
    }

    const int nb = n0 + wave * 16 + quad * 4;
    if (p < 2) {
      ushort* outp = (p == 0) ? q_t : k_t;
      #pragma unroll
      for (int lt = 0; lt < 4; ++lt) {
        const int l = l0 + lt * 16 + l16;
        #pragma unroll
        for (int r = 0; r < 4; ++r)
          outp[(size_t)(b * N_ + nb + r) * C_ + l] = f2bf(s[lt][r] + bias_l[lt]);
      }
    } else {
      #pragma unroll
      for (int lt = 0; lt < 4; ++lt) {
        const int c_out = l0 + lt * 16 + l16;
        *(ushort4*)&v_bf[(size_t)(b * C_ + c_out) * N_ + nb] =
            make_ushort4(f2bf(s[lt][0] + bias_l[lt]), f2bf(s[lt][1] + bias_l[lt]),
                         f2bf(s[lt][2] + bias_l[lt]), f2bf(s[lt][3] + bias_l[lt]));
      }
    }
    __syncthreads();
  }
}

// ---------------------------------------------------------------------------
// flash8b: R13-exact — the verified session optimum (101-102 us).
//   Eleven structural variants bracketed this on every axis (barrier
//   structure, occupancy, store paths, operand sourcing, PV shape); all
//   regressed or were neutral. Key invariants discovered:
//   (1) MFMA A-operands must come from LDS or loop-invariant regs — the
//       compiler JIT's per-iteration global-load register arrays > 32 regs
//       (R3/R14/R16: VGPR stays ~116-128, MfmaUtil halves).
//   (2) __launch_bounds__(256,2) — (256,3) caps unified VGPR+AGPR at ~170
//       < the ~188 needed -> scratch-spill thrash (R9).
//   (3) 2 blocks/CU co-residency is worth ~10% (R10); 3 doesn't materialize
//       (R12).
//   (4) Numerator partials must be written as whole 64B lines (LDS-assembled
//       coalesced stores); bf16 scatter amplifies HBM writes ~25x (R7->R8).
// grid (64, 2, 4) = (tj-blocks, i-segments, batch), block 256 (4 waves).
// ---------------------------------------------------------------------------
__global__ __launch_bounds__(256, 2) void flash8b(
    const ushort* __restrict__ q_t, const ushort* __restrict__ k_t,
    const ushort* __restrict__ v_bf, ushort* __restrict__ res0,
    ushort* __restrict__ res1, float* __restrict__ den)
{
  const int tid  = threadIdx.x;
  const int lane = tid & 63;
  const int wave = tid >> 6;
  const int l16  = lane & 15;
  const int quad = lane >> 4;
  const int jw    = blockIdx.x * 64;         // block tj base
  const int seg   = blockIdx.y;
  const int ibase = seg * 2048;              // i-segment base
  const int b     = blockIdx.z;

  const int wqk_j = wave & 1;                // QK: tj-pair (tj = wqk_j*32 + jt*16)
  const int wqk_i = wave >> 1;               // QK: i-pair  (i_loc = (wqk_i*2+itile)*16)

  __shared__ __align__(16) ushort q_lds[64 * 264];   // [i][c], +8 pad/row; reused by epilogue
  __shared__ __align__(16) ushort p_lds[64 * 72];    // [tj][ti], +8 pad/row

  // K fragments: wave's 32 tj x 256 c, resident whole kernel (64 VGPR)
  s8v kf[2][8];
  #pragma unroll
  for (int jt = 0; jt < 2; ++jt) {
    const ushort* kp = k_t + (size_t)(b * N_ + jw + wqk_j * 32 + jt * 16 + l16) * C_ + quad * 8;
    #pragma unroll
    for (int cs = 0; cs < 8; ++cs) kf[jt][cs] = *(const s8v*)(kp + cs * 32);
  }

  f4v acc[4][4];   // [m: c-tile][t: tj-tile]; c = wave*64+m*16+quad*4+r, tj = jw+t*16+l16
  #pragma unroll
  for (int m = 0; m < 4; ++m)
    #pragma unroll
    for (int t = 0; t < 4; ++t) acc[m][t] = (f4v){0.f, 0.f, 0.f, 0.f};
  float dacc0 = 0.f, dacc1 = 0.f;

  const ushort* vbase0 = v_bf + (size_t)(b * C_ + wave * 64 + l16) * N_ + quad * 8;

  for (int it = 0; it < 32; ++it) {
    const int i0 = ibase + it * 64;

    // stage q-chunk [64 i][256 c] -> LDS (8 x 16B chunks per thread)
    {
      const ushort* qseg = q_t + ((size_t)(b * N_) + i0) * C_;
      #pragma unroll
      for (int k = 0; k < 8; ++k) {
        int c = tid + k * 256;
        uint4 d = *(const uint4*)(qseg + (size_t)c * 8);
        *(uint4*)&q_lds[(c >> 5) * 264 + (c & 31) * 8] = d;
      }
    }

    // v A-frags: issue now, consumed after P-barrier
    s8v av[4][2];
    #pragma unroll
    for (int m = 0; m < 4; ++m)
      #pragma unroll
      for (int ks = 0; ks < 2; ++ks)
        av[m][ks] = *(const s8v*)(vbase0 + (size_t)(m * 16) * N_ + i0 + ks * 32);

    __syncthreads();   // q ready

    // QK: 2 i-tiles x 2 tj-tiles, A from LDS, B from registers
    #pragma unroll
    for (int itile = 0; itile < 2; ++itile) {
      const int i_loc = (wqk_i * 2 + itile) * 16;
      f4v s0 = (f4v){0.f, 0.f, 0.f, 0.f};
      f4v s1 = (f4v){0.f, 0.f, 0.f, 0.f};
      const ushort* qa_base = q_lds + (i_loc + l16) * 264 + quad * 8;
      #pragma unroll
      for (int cs = 0; cs < 8; ++cs) {
        s8v qa = *(const s8v*)(qa_base + cs * 32);
        s0 = __builtin_amdgcn_mfma_f32_16x16x32_bf16(qa, kf[0][cs], s0, 0, 0, 0);
        s1 = __builtin_amdgcn_mfma_f32_16x16x32_bf16(qa, kf[1][cs], s1, 0, 0, 0);
      }
      {
        float e0 = __expf(s0[0] * SCALE), e1 = __expf(s0[1] * SCALE);
        float e2 = __expf(s0[2] * SCALE), e3 = __expf(s0[3] * SCALE);
        dacc0 += (e0 + e1) + (e2 + e3);
        *(ushort4*)&p_lds[(wqk_j * 32 + l16) * 72 + i_loc + quad * 4] =
            make_ushort4(f2bf(e0), f2bf(e1), f2bf(e2), f2bf(e3));
      }
      {
        float e0 = __expf(s1[0] * SCALE), e1 = __expf(s1[1] * SCALE);
        float e2 = __expf(s1[2] * SCALE), e3 = __expf(s1[3] * SCALE);
        dacc1 += (e0 + e1) + (e2 + e3);
        *(ushort4*)&p_lds[(wqk_j * 32 + 16 + l16) * 72 + i_loc + quad * 4] =
            make_ushort4(f2bf(e0), f2bf(e1), f2bf(e2), f2bf(e3));
      }
    }

    __syncthreads();   // P ready (also drains av loads)

    // PV: 4 c-tiles x 4 tj-tiles, A = av regs, B from p_lds
    #pragma unroll
    for (int ks = 0; ks < 2; ++ks) {
      s8v pb[4];
      #pragma unroll
      for (int t = 0; t < 4; ++t)
        pb[t] = *(const s8v*)&p_lds[(t * 16 + l16) * 72 + ks * 32 + quad * 8];
      #pragma unroll
      for (int m = 0; m < 4; ++m)
        #pragma unroll
        for (int t = 0; t < 4; ++t)
          acc[m][t] = __builtin_amdgcn_mfma_f32_16x16x32_bf16(av[m][ks], pb[t], acc[m][t], 0, 0, 0);
    }
  }

  // ---- denom: lanes l, l^16, l^32 share tj; butterfly then atomic ----
  dacc0 += __shfl_xor(dacc0, 16);  dacc0 += __shfl_xor(dacc0, 32);
  dacc1 += __shfl_xor(dacc1, 16);  dacc1 += __shfl_xor(dacc1, 32);
  if (lane < 16) {
    atomicAdd(&den[b * N_ + jw + wqk_j * 32 + lane], dacc0);
    atomicAdd(&den[b * N_ + jw + wqk_j * 32 + 16 + lane], dacc1);
  }

  // ---- epilogue: assemble [64 j][256 c] tile in q_lds, coalesced store ----
  #pragma unroll
  for (int m = 0; m < 4; ++m) {
    const int c0 = wave * 64 + m * 16 + quad * 4;
    #pragma unroll
    for (int t = 0; t < 4; ++t) {
      *(ushort4*)&q_lds[(t * 16 + l16) * 264 + c0] =
          make_ushort4(f2bf(acc[m][t][0]), f2bf(acc[m][t][1]),
                       f2bf(acc[m][t][2]), f2bf(acc[m][t][3]));
    }
  }
  __syncthreads();   // tile assembled
  {
    ushort* rp = (seg ? res1 : res0) + (size_t)(b * N_ + jw) * C_;
    #pragma unroll
    for (int k = 0; k < 8; ++k) {
      int c = tid + k * 256;                 // 2048 16B-chunks
      int row = c >> 5, col = (c & 31) * 8;
      uint4 d = *(const uint4*)&q_lds[row * 264 + col];
      *(uint4*)&rp[(size_t)row * C_ + col] = d;
    }
  }
}

// ---------------------------------------------------------------------------
// out_mfma: out[b][co][n] = bo[co] + Wo[co][:]·(res0+res1)[b][n][:] / den[b][n]
// (R13-exact). grid (16, 4, 4), block 256.
// ---------------------------------------------------------------------------
__global__ __launch_bounds__(256, 2) void out_mfma(
    const ushort* __restrict__ res0, const ushort* __restrict__ res1,
    const float* __restrict__ Wo, const float* __restrict__ bo,
    const float* __restrict__ den, float* __restrict__ out)
{
  const int b    = blockIdx.z;
  const int co0  = blockIdx.y * 64;
  const int nseg = blockIdx.x * 256;

  const int tid  = threadIdx.x;
  const int lane = tid & 63;
  const int wave = tid >> 6;
  const int l16  = lane & 15;
  const int quad = lane >> 4;

  __shared__ __align__(16) ushort w_lds[64 * 264];
  __shared__ __align__(16) ushort r_lds[2][64 * 264];

  for (int g = tid; g < 4096; g += 256) {
    int row = g >> 6, col4 = (g & 63) * 4;
    float4 wv = *(const float4*)(Wo + (size_t)(co0 + row) * 256 + col4);
    *(ushort4*)&w_lds[row * 264 + col4] =
        make_ushort4(f2bf(wv.x), f2bf(wv.y), f2bf(wv.z), f2bf(wv.w));
  }
  __syncthreads();

  s8v kw[4][8];
  #pragma unroll
  for (int lt = 0; lt < 4; ++lt)
    #pragma unroll
    for (int cs = 0; cs < 8; ++cs)
      kw[lt][cs] = *(const s8v*)&w_lds[(lt * 16 + l16) * 264 + quad * 8 + cs * 32];

  float bias_l[4];
  #pragma unroll
  for (int lt = 0; lt < 4; ++lt) bias_l[lt] = bo[co0 + lt * 16 + l16];

  for (int it = 0; it < 4; ++it) {
    const int n0 = nseg + it * 64;
    {
      const ushort* r0 = res0 + (size_t)(b * N_ + n0) * C_;
      const ushort* r1 = res1 + (size_t)(b * N_ + n0) * C_;
      #pragma unroll
      for (int k = 0; k < 8; ++k) {
        int c = tid + k * 256;
        uint4 d0 = *(const uint4*)(r0 + (size_t)c * 8);
        uint4 d1 = *(const uint4*)(r1 + (size_t)c * 8);
        *(uint4*)&r_lds[0][(c >> 5) * 264 + (c & 31) * 8] = d0;
        *(uint4*)&r_lds[1][(c >> 5) * 264 + (c & 31) * 8] = d1;
      }
    }
    __syncthreads();

    f4v s[4];
    #pragma unroll
    for (int lt = 0; lt < 4; ++lt) s[lt] = (f4v){0.f, 0.f, 0.f, 0.f};
    #pragma unroll
    for (int buf = 0; buf < 2; ++buf) {
      const ushort* ra_base = r_lds[buf] + (wave * 16 + l16) * 264 + quad * 8;
      #pragma unroll
      for (int cs = 0; cs < 8; ++cs) {
        s8v ra = *(const s8v*)(ra_base + cs * 32);
        #pragma unroll
        for (int lt = 0; lt < 4; ++lt)
          s[lt] = __builtin_amdgcn_mfma_f32_16x16x32_bf16(ra, kw[lt][cs], s[lt], 0, 0, 0);
      }
    }

    const int nb = n0 + wave * 16 + quad * 4;
    float4 dv = *(const float4*)(den + (size_t)b * N_ + nb);
    const float di0 = 1.0f / dv.x, di1 = 1.0f / dv.y, di2 = 1.0f / dv.z, di3 = 1.0f / dv.w;
    #pragma unroll
    for (int lt = 0; lt < 4; ++lt) {
      const int co = co0 + lt * 16 + l16;
      *(float4*)&out[(size_t)(b * C_ + co) * N_ + nb] =
          make_float4(s[lt][0] * di0 + bias_l[lt], s[lt][1] * di1 + bias_l[lt],
                      s[lt][2] * di2 + bias_l[lt], s[lt][3] * di3 + bias_l[lt]);
    }
    __syncthreads();
  }
}

// ---------------------------------------------------------------------------
extern "C" void kernel_launch(void* const* d_in, const int* in_sizes, int n_in,
                              void* d_out, int out_size, void* d_ws, size_t ws_size,
                              hipStream_t stream)
{
  const float* x  = (const float*)d_in[0];
  const float* Wq = (const float*)d_in[1];
  const float* bq = (const float*)d_in[2];
  const float* Wk = (const float*)d_in[3];
  const float* bk = (const float*)d_in[4];
  const float* Wv = (const float*)d_in[5];
  const float* bv = (const float*)d_in[6];
  const float* Wo = (const float*)d_in[7];
  const float* bo = (const float*)d_in[8];
  float* out = (float*)d_out;

  // workspace layout (~48.1 MB):
  //   q_t   [B][N][L] bf16 : 8 MB   (transposed)
  //   k_t   [B][N][L] bf16 : 8 MB   (transposed)
  //   v_bf  [B][L][N] bf16 : 8 MB   (natural)
  //   res0  [B][N][L] bf16 : 8 MB   (numerator partial, i-segment 0)
  //   res1  [B][N][L] bf16 : 8 MB   (numerator partial, i-segment 1)
  //   den   [B][N]    fp32 : 64 KB  (softmax denominators; zeroed in xpose_cast)
  //   x_t   [B][N][C] bf16 : 8 MB   (transposed+cast input)
  char* ws = (char*)d_ws;
  ushort* q_t  = (ushort*)(ws);
  ushort* k_t  = (ushort*)(ws + (size_t)8  * 1024 * 1024);
  ushort* v_bf = (ushort*)(ws + (size_t)16 * 1024 * 1024);
  ushort* res0 = (ushort*)(ws + (size_t)24 * 1024 * 1024);
  ushort* res1 = (ushort*)(ws + (size_t)32 * 1024 * 1024);
  float*  den  = (float*) (ws + (size_t)40 * 1024 * 1024);
  ushort* x_t  = (ushort*)(ws + (size_t)40 * 1024 * 1024 + 65536);

  xpose_cast<<<dim3(64, 4, 4), dim3(256), 0, stream>>>(x, x_t, den);
  qkv_mfma <<<dim3(8, 4, 12),  dim3(256), 0, stream>>>(x_t, Wq, bq, Wk, bk, Wv, bv, q_t, k_t, v_bf);
  flash8b  <<<dim3(64, 2, 4),  dim3(256), 0, stream>>>(q_t, k_t, v_bf, res0, res1, den);
  out_mfma <<<dim3(16, 4, 4),  dim3(256), 0, stream>>>(res0, res1, Wo, bo, den, out);
}